// Round 9
// baseline (244.178 us; speedup 1.0000x reference)
//
#include <hip/hip_runtime.h>
#include <math.h>

#define NN 50000
#define KK 16
#define FIN 140
#define HH 8
#define HID 128

typedef __attribute__((ext_vector_type(8))) short short8;   // 8 bf16 = 4 VGPRs
typedef __attribute__((ext_vector_type(4))) float f32x4;    // MFMA acc

__device__ inline unsigned short f2bf(float f) {            // RNE fp32->bf16
  unsigned int u = __float_as_uint(f);
  return (unsigned short)((u + 0x7fffu + ((u >> 16) & 1u)) >> 16);
}
__device__ inline float bf2f(unsigned short h) {
  return __uint_as_float(((unsigned int)h) << 16);
}

// Build W^T A-operand fragment tables (hi/lo bf16 split) for pca_w and both Ws.
// A-layout for mfma_f32_16x16x32_bf16: lane L holds A[m=(L&15)][k=(L>>4)*8+j];
// m_global = t*16+(L&15) (out col), k = c*32+(L>>4)*8+j, value = W[k][m_global].
// frags layout (shorts): [pcaH 20480][pcaL 20480][W0H 16384][W0L 16384][W1H 16384][W1L 16384]
__global__ __launch_bounds__(256) void prep_kernel(
    const float* __restrict__ pca_w, const float* __restrict__ Ws,
    unsigned short* __restrict__ frags) {
  const int gid = blockIdx.x * 256 + threadIdx.x;   // 208*256 = 53248 exact
  const float* W; int K; unsigned short *dh, *dl; int tid;
  if (gid < 20480)      { W = pca_w;          K = FIN; dh = frags;                 dl = dh + 20480; tid = gid; }
  else if (gid < 36864) { W = Ws;             K = HID; dh = frags + 40960;         dl = dh + 16384; tid = gid - 20480; }
  else                  { W = Ws + HID * HID; K = HID; dh = frags + 40960 + 32768; dl = dh + 16384; tid = gid - 36864; }
  const int j = tid & 7, L = (tid >> 3) & 63, ct = tid >> 9, t = ct & 7, c = ct >> 3;
  const int k = c * 32 + (L >> 4) * 8 + j;
  const int col = t * 16 + (L & 15);
  const float v = (k < K) ? W[(size_t)k * HID + col] : 0.f;
  const unsigned short h = f2bf(v);
  dh[tid] = h;
  dl[tid] = f2bf(v - bf2f(h));
}

// x = relu(feature @ pca_w + b) -> bf16. TWO 16-node tiles per wave; weight
// fragments loaded once and used for both tiles.
__global__ __launch_bounds__(64) void pca_mfma(
    const float* __restrict__ feat, const unsigned short* __restrict__ wfh,
    const unsigned short* __restrict__ wfl, const float* __restrict__ b,
    unsigned short* __restrict__ xbf) {
  const int lane = threadIdx.x;
  const int col = lane & 15, quad = lane >> 4;
  const int tile0 = blockIdx.x * 2;
  const int tile1 = tile0 + 1;
  const bool has1 = (tile1 < NN / 16);
  const int n0 = tile0 * 16, n1 = tile1 * 16;
  f32x4 acc0[8], acc1[8];
#pragma unroll
  for (int t = 0; t < 8; ++t) {
    acc0[t] = (f32x4){0.f, 0.f, 0.f, 0.f};
    acc1[t] = (f32x4){0.f, 0.f, 0.f, 0.f};
  }
  const float* brow0 = feat + (size_t)(n0 + col) * FIN + quad * 8;
  const float* brow1 = feat + (size_t)((has1 ? n1 : n0) + col) * FIN + quad * 8;
#pragma unroll
  for (int c = 0; c < 5; ++c) {
    float4 a0, a1, c0, c1;
    if (c < 4) {
      a0 = *(const float4*)(brow0 + c * 32);
      a1 = *(const float4*)(brow0 + c * 32 + 4);
      c0 = *(const float4*)(brow1 + c * 32);
      c1 = *(const float4*)(brow1 + c * 32 + 4);
    } else {  // chunk 4: k = 128 + quad*8 + j, valid only k < 140
      a0 = make_float4(0.f, 0.f, 0.f, 0.f); a1 = a0; c0 = a0; c1 = a0;
      if (quad == 0) {
        a0 = *(const float4*)(brow0 + 128); a1 = *(const float4*)(brow0 + 132);
        c0 = *(const float4*)(brow1 + 128); c1 = *(const float4*)(brow1 + 132);
      } else if (quad == 1) {
        a0 = *(const float4*)(brow0 + 128);
        c0 = *(const float4*)(brow1 + 128);
      }
    }
    short8 B0, B1;
    B0[0] = (short)f2bf(a0.x); B0[1] = (short)f2bf(a0.y);
    B0[2] = (short)f2bf(a0.z); B0[3] = (short)f2bf(a0.w);
    B0[4] = (short)f2bf(a1.x); B0[5] = (short)f2bf(a1.y);
    B0[6] = (short)f2bf(a1.z); B0[7] = (short)f2bf(a1.w);
    B1[0] = (short)f2bf(c0.x); B1[1] = (short)f2bf(c0.y);
    B1[2] = (short)f2bf(c0.z); B1[3] = (short)f2bf(c0.w);
    B1[4] = (short)f2bf(c1.x); B1[5] = (short)f2bf(c1.y);
    B1[6] = (short)f2bf(c1.z); B1[7] = (short)f2bf(c1.w);
#pragma unroll
    for (int t = 0; t < 8; ++t) {
      const short8 Ah = *(const short8*)(wfh + ((size_t)(c * 8 + t) * 64 + lane) * 8);
      const short8 Al = *(const short8*)(wfl + ((size_t)(c * 8 + t) * 64 + lane) * 8);
      acc0[t] = __builtin_amdgcn_mfma_f32_16x16x32_bf16(Al, B0, acc0[t], 0, 0, 0);
      acc0[t] = __builtin_amdgcn_mfma_f32_16x16x32_bf16(Ah, B0, acc0[t], 0, 0, 0);
      acc1[t] = __builtin_amdgcn_mfma_f32_16x16x32_bf16(Al, B1, acc1[t], 0, 0, 0);
      acc1[t] = __builtin_amdgcn_mfma_f32_16x16x32_bf16(Ah, B1, acc1[t], 0, 0, 0);
    }
  }
#pragma unroll
  for (int t = 0; t < 8; ++t) {
    const float4 bv = *(const float4*)(b + t * 16 + quad * 4);
    {
      const float v0 = fmaxf(acc0[t][0] + bv.x, 0.f);
      const float v1 = fmaxf(acc0[t][1] + bv.y, 0.f);
      const float v2 = fmaxf(acc0[t][2] + bv.z, 0.f);
      const float v3 = fmaxf(acc0[t][3] + bv.w, 0.f);
      uint2 pk;
      pk.x = (unsigned)f2bf(v0) | ((unsigned)f2bf(v1) << 16);
      pk.y = (unsigned)f2bf(v2) | ((unsigned)f2bf(v3) << 16);
      *(uint2*)&xbf[(size_t)(n0 + col) * HID + t * 16 + quad * 4] = pk;
    }
    if (has1) {
      const float v0 = fmaxf(acc1[t][0] + bv.x, 0.f);
      const float v1 = fmaxf(acc1[t][1] + bv.y, 0.f);
      const float v2 = fmaxf(acc1[t][2] + bv.z, 0.f);
      const float v3 = fmaxf(acc1[t][3] + bv.w, 0.f);
      uint2 pk;
      pk.x = (unsigned)f2bf(v0) | ((unsigned)f2bf(v1) << 16);
      pk.y = (unsigned)f2bf(v2) | ((unsigned)f2bf(v3) << 16);
      *(uint2*)&xbf[(size_t)(n1 + col) * HID + t * 16 + quad * 4] = pk;
    }
  }
}

// h = x@W + b (bf16 store); s_src/s_dst per head. TWO tiles per wave.
__global__ __launch_bounds__(64) void proj_mfma(
    const unsigned short* __restrict__ xbf, const unsigned short* __restrict__ wfh,
    const unsigned short* __restrict__ wfl, const float* __restrict__ b,
    const float* __restrict__ asrc, const float* __restrict__ adst,
    unsigned short* __restrict__ hbf, float* __restrict__ ssrc,
    float* __restrict__ sdst) {
  const int lane = threadIdx.x;
  const int col = lane & 15, quad = lane >> 4;
  const int tile0 = blockIdx.x * 2;
  const int tile1 = tile0 + 1;
  const bool has1 = (tile1 < NN / 16);
  const int n0 = tile0 * 16, n1 = tile1 * 16;
  f32x4 acc0[8], acc1[8];
#pragma unroll
  for (int t = 0; t < 8; ++t) {
    acc0[t] = (f32x4){0.f, 0.f, 0.f, 0.f};
    acc1[t] = (f32x4){0.f, 0.f, 0.f, 0.f};
  }
  const unsigned short* brow0 = xbf + (size_t)(n0 + col) * HID + quad * 8;
  const unsigned short* brow1 = xbf + (size_t)((has1 ? n1 : n0) + col) * HID + quad * 8;
  short8 B0[4], B1[4];
#pragma unroll
  for (int c = 0; c < 4; ++c) {
    B0[c] = *(const short8*)(brow0 + c * 32);
    B1[c] = *(const short8*)(brow1 + c * 32);
  }
#pragma unroll
  for (int c = 0; c < 4; ++c) {
#pragma unroll
    for (int t = 0; t < 8; ++t) {
      const short8 Ah = *(const short8*)(wfh + ((size_t)(c * 8 + t) * 64 + lane) * 8);
      const short8 Al = *(const short8*)(wfl + ((size_t)(c * 8 + t) * 64 + lane) * 8);
      acc0[t] = __builtin_amdgcn_mfma_f32_16x16x32_bf16(Al, B0[c], acc0[t], 0, 0, 0);
      acc0[t] = __builtin_amdgcn_mfma_f32_16x16x32_bf16(Ah, B0[c], acc0[t], 0, 0, 0);
      acc1[t] = __builtin_amdgcn_mfma_f32_16x16x32_bf16(Al, B1[c], acc1[t], 0, 0, 0);
      acc1[t] = __builtin_amdgcn_mfma_f32_16x16x32_bf16(Ah, B1[c], acc1[t], 0, 0, 0);
    }
  }
  // lane holds node base+col, out-cols t*16+quad*4+r (head == t)
#pragma unroll
  for (int t = 0; t < 8; ++t) {
    const float4 bv = *(const float4*)(b + t * 16 + quad * 4);
    const float4 av = *(const float4*)(asrc + t * 16 + quad * 4);
    const float4 dv = *(const float4*)(adst + t * 16 + quad * 4);
#pragma unroll
    for (int p = 0; p < 2; ++p) {
      if (p == 1 && !has1) break;
      const f32x4& a = p ? acc1[t] : acc0[t];
      const int nb_ = p ? n1 : n0;
      const float v0 = a[0] + bv.x;
      const float v1 = a[1] + bv.y;
      const float v2 = a[2] + bv.z;
      const float v3 = a[3] + bv.w;
      uint2 pk;
      pk.x = (unsigned)f2bf(v0) | ((unsigned)f2bf(v1) << 16);
      pk.y = (unsigned)f2bf(v2) | ((unsigned)f2bf(v3) << 16);
      *(uint2*)&hbf[(size_t)(nb_ + col) * HID + t * 16 + quad * 4] = pk;
      float ps = v0 * av.x + v1 * av.y + v2 * av.z + v3 * av.w;
      float pd = v0 * dv.x + v1 * dv.y + v2 * dv.z + v3 * dv.w;
      ps += __shfl_xor(ps, 16); ps += __shfl_xor(ps, 32);
      pd += __shfl_xor(pd, 16); pd += __shfl_xor(pd, 32);
      if (quad == 0) ssrc[(size_t)(nb_ + col) * HH + t] = ps;
      if (quad == 1) sdst[(size_t)(nb_ + col) * HH + t] = pd;
    }
  }
}

// attn body: one wave handles FOUR nodes per iteration (~64 outstanding
// gathers issued before the four interleaved softmax chains).
template <bool LAST>
__device__ inline void attn_body(
    const int* __restrict__ nb, const unsigned int* __restrict__ hbf,
    const float* __restrict__ ssrc, const float* __restrict__ sdst,
    void* __restrict__ xout, int lane, int wid, int nwaves) {
  const int h = lane & 7, k0 = lane >> 3;             // lane = k0*8 + h
  const int head = lane >> 3;                         // cols 2*lane, 2*lane+1
  for (int base = wid * 4; base < NN; base += nwaves * 4) {  // NN % 4 == 0
    // lane c*16+k loads nb[(base+c)*16+k]  (64 lanes = 4 nodes x 16 nbrs)
    const int nbv = nb[(size_t)(base + (lane >> 4)) * KK + (lane & 15)];
    unsigned int u[4][KK];
#pragma unroll
    for (int n = 0; n < 4; ++n)
#pragma unroll
      for (int k = 0; k < KK; ++k) {
        const int r = __shfl(nbv, n * KK + k);
        u[n][k] = hbf[(size_t)r * (HID / 2) + lane];
      }
    float e0[4], e1[4], m[4], p0[4], p1[4], s[4];
#pragma unroll
    for (int n = 0; n < 4; ++n) {
      const int r0 = __shfl(nbv, n * KK + k0);
      const int r1 = __shfl(nbv, n * KK + k0 + 8);
      const float ss = ssrc[(size_t)(base + n) * HH + h];
      e0[n] = ss + sdst[(size_t)r0 * HH + h];
      e1[n] = ss + sdst[(size_t)r1 * HH + h];
      e0[n] = e0[n] > 0.f ? e0[n] : 0.2f * e0[n];
      e1[n] = e1[n] > 0.f ? e1[n] : 0.2f * e1[n];
      m[n] = fmaxf(e0[n], e1[n]);
    }
#pragma unroll
    for (int n = 0; n < 4; ++n) m[n] = fmaxf(m[n], __shfl_xor(m[n], 8));
#pragma unroll
    for (int n = 0; n < 4; ++n) m[n] = fmaxf(m[n], __shfl_xor(m[n], 16));
#pragma unroll
    for (int n = 0; n < 4; ++n) m[n] = fmaxf(m[n], __shfl_xor(m[n], 32));
#pragma unroll
    for (int n = 0; n < 4; ++n) {
      p0[n] = __expf(e0[n] - m[n]);
      p1[n] = __expf(e1[n] - m[n]);
      s[n] = p0[n] + p1[n];
    }
#pragma unroll
    for (int n = 0; n < 4; ++n) s[n] += __shfl_xor(s[n], 8);
#pragma unroll
    for (int n = 0; n < 4; ++n) s[n] += __shfl_xor(s[n], 16);
#pragma unroll
    for (int n = 0; n < 4; ++n) s[n] += __shfl_xor(s[n], 32);
#pragma unroll
    for (int n = 0; n < 4; ++n) {
      const float inv = 1.f / s[n];
      p0[n] *= inv; p1[n] *= inv;
    }
    float a0[4] = {0.f, 0.f, 0.f, 0.f}, a1[4] = {0.f, 0.f, 0.f, 0.f};
#pragma unroll
    for (int k = 0; k < KK; ++k) {
      const int src = ((k & 7) << 3) + head;
#pragma unroll
      for (int n = 0; n < 4; ++n) {
        const float sel = (k < 8) ? p0[n] : p1[n];
        const float w = __shfl(sel, src);
        a0[n] = fmaf(w, __uint_as_float(u[n][k] << 16), a0[n]);
        a1[n] = fmaf(w, __uint_as_float(u[n][k] & 0xffff0000u), a1[n]);
      }
    }
#pragma unroll
    for (int n = 0; n < 4; ++n) {
      const float o0 = a0[n] > 0.f ? a0[n] : __expf(a0[n]) - 1.f;
      const float o1 = a1[n] > 0.f ? a1[n] : __expf(a1[n]) - 1.f;
      if (LAST) {
        *(float2*)((float*)xout + (size_t)(base + n) * HID + 2 * lane) =
            make_float2(o0, o1);
      } else {
        ((unsigned int*)xout)[(size_t)(base + n) * (HID / 2) + lane] =
            (unsigned)f2bf(o0) | ((unsigned)f2bf(o1) << 16);
      }
    }
  }
}

__global__ __launch_bounds__(256) void attn0_kernel(
    const int* __restrict__ nb, const unsigned int* __restrict__ hbf,
    const float* __restrict__ ssrc, const float* __restrict__ sdst,
    unsigned short* __restrict__ xbf) {
  const int lane = threadIdx.x & 63;
  const int wid = (blockIdx.x << 2) + (threadIdx.x >> 6);
  attn_body<false>(nb, hbf, ssrc, sdst, (void*)xbf, lane, wid, gridDim.x << 2);
}

__global__ __launch_bounds__(256) void attn1_kernel(
    const int* __restrict__ nb, const unsigned int* __restrict__ hbf,
    const float* __restrict__ ssrc, const float* __restrict__ sdst,
    float* __restrict__ out) {
  const int lane = threadIdx.x & 63;
  const int wid = (blockIdx.x << 2) + (threadIdx.x >> 6);
  attn_body<true>(nb, hbf, ssrc, sdst, (void*)out, lane, wid, gridDim.x << 2);
}

extern "C" void kernel_launch(void* const* d_in, const int* in_sizes, int n_in,
                              void* d_out, int out_size, void* d_ws, size_t ws_size,
                              hipStream_t stream) {
  const float* feature = (const float*)d_in[0];
  const int*   nb      = (const int*)d_in[1];
  const float* pca_w   = (const float*)d_in[2];
  const float* pca_b   = (const float*)d_in[3];
  const float* Ws      = (const float*)d_in[4];
  const float* bs      = (const float*)d_in[5];
  const float* a_src   = (const float*)d_in[6];
  const float* a_dst   = (const float*)d_in[7];
  float* out = (float*)d_out;

  unsigned short* xbf = (unsigned short*)d_ws;                 // [N,128] bf16
  unsigned short* hbf = xbf + (size_t)NN * HID;                // [N,128] bf16
  float* ssrc = (float*)(hbf + (size_t)NN * HID);              // [N,8]
  float* sdst = ssrc + (size_t)NN * HH;                        // [N,8]
  unsigned short* frags = (unsigned short*)(sdst + (size_t)NN * HH); // 106496 shorts

  const int ntile2 = (NN / 16 + 1) / 2;   // 1563 blocks, 2 tiles/wave
  prep_kernel<<<208, 256, 0, stream>>>(pca_w, Ws, frags);
  pca_mfma<<<ntile2, 64, 0, stream>>>(feature, frags, frags + 20480, pca_b, xbf);
  for (int l = 0; l < 2; ++l) {
    const unsigned short* wh = frags + 40960 + (size_t)l * 32768;
    proj_mfma<<<ntile2, 64, 0, stream>>>(
        xbf, wh, wh + 16384, bs + (size_t)l * HID,
        a_src + (size_t)l * HID, a_dst + (size_t)l * HID, hbf, ssrc, sdst);
    if (l == 1)
      attn1_kernel<<<2048, 256, 0, stream>>>(nb, (const unsigned int*)hbf,
                                             ssrc, sdst, out);
    else
      attn0_kernel<<<2048, 256, 0, stream>>>(nb, (const unsigned int*)hbf,
                                             ssrc, sdst, xbf);
  }
}

// Round 10
// 206.166 us; speedup vs baseline: 1.1844x; 1.1844x over previous
//
#include <hip/hip_runtime.h>
#include <math.h>

#define NN 50000
#define KK 16
#define FIN 140
#define HH 8
#define HID 128

typedef __attribute__((ext_vector_type(8))) short short8;   // 8 bf16 = 4 VGPRs
typedef __attribute__((ext_vector_type(4))) float f32x4;    // MFMA acc

__device__ inline unsigned short f2bf(float f) {            // RNE fp32->bf16
  unsigned int u = __float_as_uint(f);
  return (unsigned short)((u + 0x7fffu + ((u >> 16) & 1u)) >> 16);
}
__device__ inline float bf2f(unsigned short h) {
  return __uint_as_float(((unsigned int)h) << 16);
}

// Build W^T A-operand fragment tables (hi/lo bf16 split) for pca_w and both Ws.
// A-layout for mfma_f32_16x16x32_bf16: lane L holds A[m=(L&15)][k=(L>>4)*8+j];
// m_global = t*16+(L&15) (out col), k = c*32+(L>>4)*8+j, value = W[k][m_global].
// frags layout (shorts): [pcaH 20480][pcaL 20480][W0H 16384][W0L 16384][W1H 16384][W1L 16384]
__global__ __launch_bounds__(256) void prep_kernel(
    const float* __restrict__ pca_w, const float* __restrict__ Ws,
    unsigned short* __restrict__ frags) {
  const int gid = blockIdx.x * 256 + threadIdx.x;   // 208*256 = 53248 exact
  const float* W; int K; unsigned short *dh, *dl; int tid;
  if (gid < 20480)      { W = pca_w;          K = FIN; dh = frags;                 dl = dh + 20480; tid = gid; }
  else if (gid < 36864) { W = Ws;             K = HID; dh = frags + 40960;         dl = dh + 16384; tid = gid - 20480; }
  else                  { W = Ws + HID * HID; K = HID; dh = frags + 40960 + 32768; dl = dh + 16384; tid = gid - 36864; }
  const int j = tid & 7, L = (tid >> 3) & 63, ct = tid >> 9, t = ct & 7, c = ct >> 3;
  const int k = c * 32 + (L >> 4) * 8 + j;
  const int col = t * 16 + (L & 15);
  const float v = (k < K) ? W[(size_t)k * HID + col] : 0.f;
  const unsigned short h = f2bf(v);
  dh[tid] = h;
  dl[tid] = f2bf(v - bf2f(h));
}

// x = relu(feature @ pca_w + b) -> bf16. TWO 16-node tiles per wave; weight
// fragments loaded once and used for both tiles.
__global__ __launch_bounds__(64) void pca_mfma(
    const float* __restrict__ feat, const unsigned short* __restrict__ wfh,
    const unsigned short* __restrict__ wfl, const float* __restrict__ b,
    unsigned short* __restrict__ xbf) {
  const int lane = threadIdx.x;
  const int col = lane & 15, quad = lane >> 4;
  const int tile0 = blockIdx.x * 2;
  const int tile1 = tile0 + 1;
  const bool has1 = (tile1 < NN / 16);
  const int n0 = tile0 * 16, n1 = tile1 * 16;
  f32x4 acc0[8], acc1[8];
#pragma unroll
  for (int t = 0; t < 8; ++t) {
    acc0[t] = (f32x4){0.f, 0.f, 0.f, 0.f};
    acc1[t] = (f32x4){0.f, 0.f, 0.f, 0.f};
  }
  const float* brow0 = feat + (size_t)(n0 + col) * FIN + quad * 8;
  const float* brow1 = feat + (size_t)((has1 ? n1 : n0) + col) * FIN + quad * 8;
#pragma unroll
  for (int c = 0; c < 5; ++c) {
    float4 a0, a1, c0, c1;
    if (c < 4) {
      a0 = *(const float4*)(brow0 + c * 32);
      a1 = *(const float4*)(brow0 + c * 32 + 4);
      c0 = *(const float4*)(brow1 + c * 32);
      c1 = *(const float4*)(brow1 + c * 32 + 4);
    } else {  // chunk 4: k = 128 + quad*8 + j, valid only k < 140
      a0 = make_float4(0.f, 0.f, 0.f, 0.f); a1 = a0; c0 = a0; c1 = a0;
      if (quad == 0) {
        a0 = *(const float4*)(brow0 + 128); a1 = *(const float4*)(brow0 + 132);
        c0 = *(const float4*)(brow1 + 128); c1 = *(const float4*)(brow1 + 132);
      } else if (quad == 1) {
        a0 = *(const float4*)(brow0 + 128);
        c0 = *(const float4*)(brow1 + 128);
      }
    }
    short8 B0, B1;
    B0[0] = (short)f2bf(a0.x); B0[1] = (short)f2bf(a0.y);
    B0[2] = (short)f2bf(a0.z); B0[3] = (short)f2bf(a0.w);
    B0[4] = (short)f2bf(a1.x); B0[5] = (short)f2bf(a1.y);
    B0[6] = (short)f2bf(a1.z); B0[7] = (short)f2bf(a1.w);
    B1[0] = (short)f2bf(c0.x); B1[1] = (short)f2bf(c0.y);
    B1[2] = (short)f2bf(c0.z); B1[3] = (short)f2bf(c0.w);
    B1[4] = (short)f2bf(c1.x); B1[5] = (short)f2bf(c1.y);
    B1[6] = (short)f2bf(c1.z); B1[7] = (short)f2bf(c1.w);
#pragma unroll
    for (int t = 0; t < 8; ++t) {
      const short8 Ah = *(const short8*)(wfh + ((size_t)(c * 8 + t) * 64 + lane) * 8);
      const short8 Al = *(const short8*)(wfl + ((size_t)(c * 8 + t) * 64 + lane) * 8);
      acc0[t] = __builtin_amdgcn_mfma_f32_16x16x32_bf16(Al, B0, acc0[t], 0, 0, 0);
      acc0[t] = __builtin_amdgcn_mfma_f32_16x16x32_bf16(Ah, B0, acc0[t], 0, 0, 0);
      acc1[t] = __builtin_amdgcn_mfma_f32_16x16x32_bf16(Al, B1, acc1[t], 0, 0, 0);
      acc1[t] = __builtin_amdgcn_mfma_f32_16x16x32_bf16(Ah, B1, acc1[t], 0, 0, 0);
    }
  }
#pragma unroll
  for (int t = 0; t < 8; ++t) {
    const float4 bv = *(const float4*)(b + t * 16 + quad * 4);
    {
      const float v0 = fmaxf(acc0[t][0] + bv.x, 0.f);
      const float v1 = fmaxf(acc0[t][1] + bv.y, 0.f);
      const float v2 = fmaxf(acc0[t][2] + bv.z, 0.f);
      const float v3 = fmaxf(acc0[t][3] + bv.w, 0.f);
      uint2 pk;
      pk.x = (unsigned)f2bf(v0) | ((unsigned)f2bf(v1) << 16);
      pk.y = (unsigned)f2bf(v2) | ((unsigned)f2bf(v3) << 16);
      *(uint2*)&xbf[(size_t)(n0 + col) * HID + t * 16 + quad * 4] = pk;
    }
    if (has1) {
      const float v0 = fmaxf(acc1[t][0] + bv.x, 0.f);
      const float v1 = fmaxf(acc1[t][1] + bv.y, 0.f);
      const float v2 = fmaxf(acc1[t][2] + bv.z, 0.f);
      const float v3 = fmaxf(acc1[t][3] + bv.w, 0.f);
      uint2 pk;
      pk.x = (unsigned)f2bf(v0) | ((unsigned)f2bf(v1) << 16);
      pk.y = (unsigned)f2bf(v2) | ((unsigned)f2bf(v3) << 16);
      *(uint2*)&xbf[(size_t)(n1 + col) * HID + t * 16 + quad * 4] = pk;
    }
  }
}

// h = x@W + b (bf16 store); s_src/s_dst per head. TWO tiles per wave.
__global__ __launch_bounds__(64) void proj_mfma(
    const unsigned short* __restrict__ xbf, const unsigned short* __restrict__ wfh,
    const unsigned short* __restrict__ wfl, const float* __restrict__ b,
    const float* __restrict__ asrc, const float* __restrict__ adst,
    unsigned short* __restrict__ hbf, float* __restrict__ ssrc,
    float* __restrict__ sdst) {
  const int lane = threadIdx.x;
  const int col = lane & 15, quad = lane >> 4;
  const int tile0 = blockIdx.x * 2;
  const int tile1 = tile0 + 1;
  const bool has1 = (tile1 < NN / 16);
  const int n0 = tile0 * 16, n1 = tile1 * 16;
  f32x4 acc0[8], acc1[8];
#pragma unroll
  for (int t = 0; t < 8; ++t) {
    acc0[t] = (f32x4){0.f, 0.f, 0.f, 0.f};
    acc1[t] = (f32x4){0.f, 0.f, 0.f, 0.f};
  }
  const unsigned short* brow0 = xbf + (size_t)(n0 + col) * HID + quad * 8;
  const unsigned short* brow1 = xbf + (size_t)((has1 ? n1 : n0) + col) * HID + quad * 8;
  short8 B0[4], B1[4];
#pragma unroll
  for (int c = 0; c < 4; ++c) {
    B0[c] = *(const short8*)(brow0 + c * 32);
    B1[c] = *(const short8*)(brow1 + c * 32);
  }
#pragma unroll
  for (int c = 0; c < 4; ++c) {
#pragma unroll
    for (int t = 0; t < 8; ++t) {
      const short8 Ah = *(const short8*)(wfh + ((size_t)(c * 8 + t) * 64 + lane) * 8);
      const short8 Al = *(const short8*)(wfl + ((size_t)(c * 8 + t) * 64 + lane) * 8);
      acc0[t] = __builtin_amdgcn_mfma_f32_16x16x32_bf16(Al, B0[c], acc0[t], 0, 0, 0);
      acc0[t] = __builtin_amdgcn_mfma_f32_16x16x32_bf16(Ah, B0[c], acc0[t], 0, 0, 0);
      acc1[t] = __builtin_amdgcn_mfma_f32_16x16x32_bf16(Al, B1[c], acc1[t], 0, 0, 0);
      acc1[t] = __builtin_amdgcn_mfma_f32_16x16x32_bf16(Ah, B1[c], acc1[t], 0, 0, 0);
    }
  }
  // lane holds node base+col, out-cols t*16+quad*4+r (head == t)
#pragma unroll
  for (int t = 0; t < 8; ++t) {
    const float4 bv = *(const float4*)(b + t * 16 + quad * 4);
    const float4 av = *(const float4*)(asrc + t * 16 + quad * 4);
    const float4 dv = *(const float4*)(adst + t * 16 + quad * 4);
#pragma unroll
    for (int p = 0; p < 2; ++p) {
      if (p == 1 && !has1) break;
      const f32x4& a = p ? acc1[t] : acc0[t];
      const int nb_ = p ? n1 : n0;
      const float v0 = a[0] + bv.x;
      const float v1 = a[1] + bv.y;
      const float v2 = a[2] + bv.z;
      const float v3 = a[3] + bv.w;
      uint2 pk;
      pk.x = (unsigned)f2bf(v0) | ((unsigned)f2bf(v1) << 16);
      pk.y = (unsigned)f2bf(v2) | ((unsigned)f2bf(v3) << 16);
      *(uint2*)&hbf[(size_t)(nb_ + col) * HID + t * 16 + quad * 4] = pk;
      float ps = v0 * av.x + v1 * av.y + v2 * av.z + v3 * av.w;
      float pd = v0 * dv.x + v1 * dv.y + v2 * dv.z + v3 * dv.w;
      ps += __shfl_xor(ps, 16); ps += __shfl_xor(ps, 32);
      pd += __shfl_xor(pd, 16); pd += __shfl_xor(pd, 32);
      if (quad == 0) ssrc[(size_t)(nb_ + col) * HH + t] = ps;
      if (quad == 1) sdst[(size_t)(nb_ + col) * HH + t] = pd;
    }
  }
}

// attn body: one wave handles a PAIR of nodes per iteration (2-node ILP:
// ~36 outstanding loads issued before either softmax chain). 2-node is the
// VGPR sweet spot: 4-node (u[4][16]) exceeded the allocator budget and the
// compiler sank the gathers below the softmax (R9 regression, VGPR=52).
template <bool LAST>
__device__ inline void attn_body(
    const int* __restrict__ nb, const unsigned int* __restrict__ hbf,
    const float* __restrict__ ssrc, const float* __restrict__ sdst,
    void* __restrict__ xout, int lane, int wid, int nwaves) {
  for (int base = wid * 2; base < NN; base += nwaves * 2) {
    const int nA = base, nB = base + 1;
    // lanes 0..15 load nb[nA], lanes 16..31 load nb[nB]
    int nbv = 0;
    if (lane < KK) nbv = nb[(size_t)nA * KK + lane];
    else if (lane < 2 * KK) nbv = nb[(size_t)nB * KK + (lane - KK)];
    unsigned int uA[KK], uB[KK];
#pragma unroll
    for (int k = 0; k < KK; ++k) {
      const int rA = __shfl(nbv, k);
      uA[k] = hbf[(size_t)rA * (HID / 2) + lane];
    }
#pragma unroll
    for (int k = 0; k < KK; ++k) {
      const int rB = __shfl(nbv, KK + k);
      uB[k] = hbf[(size_t)rB * (HID / 2) + lane];
    }
    const int h = lane & 7, k0 = lane >> 3;           // lane = k0*8 + h
    const int rA0 = __shfl(nbv, k0), rA1 = __shfl(nbv, k0 + 8);
    const int rB0 = __shfl(nbv, KK + k0), rB1 = __shfl(nbv, KK + k0 + 8);
    const float ssA = ssrc[(size_t)nA * HH + h];
    const float ssB = ssrc[(size_t)nB * HH + h];
    float eA0 = ssA + sdst[(size_t)rA0 * HH + h];
    float eA1 = ssA + sdst[(size_t)rA1 * HH + h];
    float eB0 = ssB + sdst[(size_t)rB0 * HH + h];
    float eB1 = ssB + sdst[(size_t)rB1 * HH + h];
    eA0 = eA0 > 0.f ? eA0 : 0.2f * eA0;
    eA1 = eA1 > 0.f ? eA1 : 0.2f * eA1;
    eB0 = eB0 > 0.f ? eB0 : 0.2f * eB0;
    eB1 = eB1 > 0.f ? eB1 : 0.2f * eB1;
    float mA = fmaxf(eA0, eA1), mB = fmaxf(eB0, eB1);
    mA = fmaxf(mA, __shfl_xor(mA, 8));  mB = fmaxf(mB, __shfl_xor(mB, 8));
    mA = fmaxf(mA, __shfl_xor(mA, 16)); mB = fmaxf(mB, __shfl_xor(mB, 16));
    mA = fmaxf(mA, __shfl_xor(mA, 32)); mB = fmaxf(mB, __shfl_xor(mB, 32));
    float pA0 = __expf(eA0 - mA), pA1 = __expf(eA1 - mA);
    float pB0 = __expf(eB0 - mB), pB1 = __expf(eB1 - mB);
    float sA = pA0 + pA1, sB = pB0 + pB1;
    sA += __shfl_xor(sA, 8);  sB += __shfl_xor(sB, 8);
    sA += __shfl_xor(sA, 16); sB += __shfl_xor(sB, 16);
    sA += __shfl_xor(sA, 32); sB += __shfl_xor(sB, 32);
    const float invA = 1.f / sA, invB = 1.f / sB;
    pA0 *= invA; pA1 *= invA; pB0 *= invB; pB1 *= invB;
    const int head = lane >> 3;                       // cols 2*lane, 2*lane+1
    float aA0 = 0.f, aA1 = 0.f, aB0 = 0.f, aB1 = 0.f;
#pragma unroll
    for (int k = 0; k < KK; ++k) {
      const float selA = (k < 8) ? pA0 : pA1;
      const float selB = (k < 8) ? pB0 : pB1;
      const float wA = __shfl(selA, ((k & 7) << 3) + head);
      const float wB = __shfl(selB, ((k & 7) << 3) + head);
      aA0 = fmaf(wA, __uint_as_float(uA[k] << 16), aA0);
      aA1 = fmaf(wA, __uint_as_float(uA[k] & 0xffff0000u), aA1);
      aB0 = fmaf(wB, __uint_as_float(uB[k] << 16), aB0);
      aB1 = fmaf(wB, __uint_as_float(uB[k] & 0xffff0000u), aB1);
    }
    const float oA0 = aA0 > 0.f ? aA0 : __expf(aA0) - 1.f;
    const float oA1 = aA1 > 0.f ? aA1 : __expf(aA1) - 1.f;
    const float oB0 = aB0 > 0.f ? aB0 : __expf(aB0) - 1.f;
    const float oB1 = aB1 > 0.f ? aB1 : __expf(aB1) - 1.f;
    if (LAST) {
      *(float2*)((float*)xout + (size_t)nA * HID + 2 * lane) = make_float2(oA0, oA1);
      *(float2*)((float*)xout + (size_t)nB * HID + 2 * lane) = make_float2(oB0, oB1);
    } else {
      ((unsigned int*)xout)[(size_t)nA * (HID / 2) + lane] =
          (unsigned)f2bf(oA0) | ((unsigned)f2bf(oA1) << 16);
      ((unsigned int*)xout)[(size_t)nB * (HID / 2) + lane] =
          (unsigned)f2bf(oB0) | ((unsigned)f2bf(oB1) << 16);
    }
  }
}

__global__ __launch_bounds__(256) void attn0_kernel(
    const int* __restrict__ nb, const unsigned int* __restrict__ hbf,
    const float* __restrict__ ssrc, const float* __restrict__ sdst,
    unsigned short* __restrict__ xbf) {
  const int lane = threadIdx.x & 63;
  const int wid = (blockIdx.x << 2) + (threadIdx.x >> 6);
  attn_body<false>(nb, hbf, ssrc, sdst, (void*)xbf, lane, wid, gridDim.x << 2);
}

__global__ __launch_bounds__(256) void attn1_kernel(
    const int* __restrict__ nb, const unsigned int* __restrict__ hbf,
    const float* __restrict__ ssrc, const float* __restrict__ sdst,
    float* __restrict__ out) {
  const int lane = threadIdx.x & 63;
  const int wid = (blockIdx.x << 2) + (threadIdx.x >> 6);
  attn_body<true>(nb, hbf, ssrc, sdst, (void*)out, lane, wid, gridDim.x << 2);
}

extern "C" void kernel_launch(void* const* d_in, const int* in_sizes, int n_in,
                              void* d_out, int out_size, void* d_ws, size_t ws_size,
                              hipStream_t stream) {
  const float* feature = (const float*)d_in[0];
  const int*   nb      = (const int*)d_in[1];
  const float* pca_w   = (const float*)d_in[2];
  const float* pca_b   = (const float*)d_in[3];
  const float* Ws      = (const float*)d_in[4];
  const float* bs      = (const float*)d_in[5];
  const float* a_src   = (const float*)d_in[6];
  const float* a_dst   = (const float*)d_in[7];
  float* out = (float*)d_out;

  unsigned short* xbf = (unsigned short*)d_ws;                 // [N,128] bf16
  unsigned short* hbf = xbf + (size_t)NN * HID;                // [N,128] bf16
  float* ssrc = (float*)(hbf + (size_t)NN * HID);              // [N,8]
  float* sdst = ssrc + (size_t)NN * HH;                        // [N,8]
  unsigned short* frags = (unsigned short*)(sdst + (size_t)NN * HH); // 106496 shorts

  const int ntile2 = (NN / 16 + 1) / 2;   // 1563 blocks, 2 tiles/wave
  prep_kernel<<<208, 256, 0, stream>>>(pca_w, Ws, frags);
  pca_mfma<<<ntile2, 64, 0, stream>>>(feature, frags, frags + 20480, pca_b, xbf);
  for (int l = 0; l < 2; ++l) {
    const unsigned short* wh = frags + 40960 + (size_t)l * 32768;
    proj_mfma<<<ntile2, 64, 0, stream>>>(
        xbf, wh, wh + 16384, bs + (size_t)l * HID,
        a_src + (size_t)l * HID, a_dst + (size_t)l * HID, hbf, ssrc, sdst);
    if (l == 1)
      attn1_kernel<<<2048, 256, 0, stream>>>(nb, (const unsigned int*)hbf,
                                             ssrc, sdst, out);
    else
      attn0_kernel<<<2048, 256, 0, stream>>>(nb, (const unsigned int*)hbf,
                                             ssrc, sdst, xbf);
  }
}